// Round 6
// baseline (256.651 us; speedup 1.0000x reference)
//
#include <hip/hip_runtime.h>
#include <hip/hip_bf16.h>

// Shapes (fixed problem)
#define BSZ   8192
#define DIN   1024
#define DOUT  512
#define NEXP  4

typedef __attribute__((ext_vector_type(8))) short short8;
typedef __attribute__((ext_vector_type(4))) float f32x4;

// ---------- helpers ----------
static __device__ inline unsigned short f32_to_bf16_rne(float f) {
    unsigned int u = __float_as_uint(f);
    unsigned int r = 0x7FFFu + ((u >> 16) & 1u);
    u += r;
    return (unsigned short)(u >> 16);
}

static __device__ inline float bf16_to_f32(unsigned short u) {
    return __uint_as_float(((unsigned int)u) << 16);
}

static __device__ inline float wred(float v) {  // full-wave butterfly sum
    for (int off = 1; off < 64; off <<= 1) v += __shfl_xor(v, off, 64);
    return v;
}

#define GLD_LDS16(g, l)                                                        \
    __builtin_amdgcn_global_load_lds(                                          \
        (const __attribute__((address_space(1))) void*)(g),                    \
        (__attribute__((address_space(3))) void*)(l), 16, 0, 0)

// ---------- 1. prep: x->bf16 | W->Wt bf16 transposed | zero Z --------------
// blocks 0..4095: convx (8 elems/thread). blocks 4096..6143: convwt tiles.
__global__ __launch_bounds__(256) void prep_kernel(
    const float* __restrict__ x, const float* __restrict__ W,
    unsigned short* __restrict__ xb, unsigned short* __restrict__ Wt,
    float* __restrict__ Z) {
    __shared__ float tile[32][33];
    const int bid = blockIdx.x;
    if (bid < 4096) {
        if (bid == 0 && threadIdx.x < 4) Z[threadIdx.x] = 0.0f;
        size_t i = ((size_t)bid * 256 + threadIdx.x) * 8;
        float4 v0 = *(const float4*)&x[i];
        float4 v1 = *(const float4*)&x[i + 4];
        unsigned short tmp[8] = {
            f32_to_bf16_rne(v0.x), f32_to_bf16_rne(v0.y),
            f32_to_bf16_rne(v0.z), f32_to_bf16_rne(v0.w),
            f32_to_bf16_rne(v1.x), f32_to_bf16_rne(v1.y),
            f32_to_bf16_rne(v1.z), f32_to_bf16_rne(v1.w)};
        *(short8*)&xb[i] = *(short8*)tmp;
    } else {
        const int id = bid - 4096;
        const int e = id >> 9;
        const int rem = id & 511;
        const int k0 = (rem >> 4) << 5;
        const int n0 = (rem & 15) << 5;
        const int c = threadIdx.x & 31, r4 = threadIdx.x >> 5;
        const float* Wp = W + ((size_t)e * DIN + k0) * DOUT + n0;
#pragma unroll
        for (int i = 0; i < 4; ++i) {
            int r = r4 + i * 8;
            tile[r][c] = Wp[(size_t)r * DOUT + c];
        }
        __syncthreads();
        unsigned short* Wtp = Wt + ((size_t)e * DOUT + n0) * DIN + k0;
#pragma unroll
        for (int i = 0; i < 4; ++i) {
            int r = r4 + i * 8;
            Wtp[(size_t)r * DIN + c] = f32_to_bf16_rne(tile[c][r]);
        }
    }
}

// ---------- 2. GEMM: 128x128 tile, BK=32, double-buffered LDS (2-phase) ----
// One barrier per K-step: STAGE(next) issued before ds_read+MFMA(cur).
__global__ __launch_bounds__(256) void gemm_kernel(
    const unsigned short* __restrict__ xb,
    const unsigned short* __restrict__ wtb,
    const float* __restrict__ bias,
    unsigned short* __restrict__ lgts) {
    __shared__ unsigned short As[2][128 * 32];
    __shared__ unsigned short Bs[2][128 * 32];
    const int tid = threadIdx.x;

    // bijective XCD swizzle (1024 % 8 == 0): each XCD owns 8 m-panels x all (e,n)
    const int bid = blockIdx.x;
    const int swz = (bid & 7) * 128 + (bid >> 3);
    const int mt = swz >> 4;
    const int e  = (swz >> 2) & 3;
    const int nt = swz & 3;
    const int m0 = mt * 128;
    const int n0 = nt * 128;

    const unsigned short* Ag = xb + (size_t)m0 * DIN;
    const unsigned short* Bg = wtb + ((size_t)e * DOUT + n0) * DIN;

    const int lane = tid & 63, w = tid >> 6;
    const int wm = (w >> 1) * 64, wn = (w & 1) * 64;
    const int kk = (lane >> 4) * 8, rr = lane & 15;

    f32x4 acc[4][4] = {};

    const int f = tid;
    const int row0 = f >> 2, seg0 = f & 3;
    const int f1 = 256 + tid;
    const int row1 = f1 >> 2, seg1 = f1 & 3;

#define STAGE(buf, kt)                                                         \
    do {                                                                       \
        const int k0_ = (kt) * 32;                                             \
        GLD_LDS16(Ag + (size_t)row0 * DIN + k0_ + seg0 * 8, &As[buf][f * 8]);  \
        GLD_LDS16(Bg + (size_t)row0 * DIN + k0_ + seg0 * 8, &Bs[buf][f * 8]);  \
        GLD_LDS16(Ag + (size_t)row1 * DIN + k0_ + seg1 * 8, &As[buf][f1 * 8]); \
        GLD_LDS16(Bg + (size_t)row1 * DIN + k0_ + seg1 * 8, &Bs[buf][f1 * 8]); \
    } while (0)

#define COMPUTE(buf)                                                           \
    do {                                                                       \
        short8 a[4], b[4];                                                     \
        _Pragma("unroll") for (int i = 0; i < 4; ++i)                          \
            a[i] = *(const short8*)&As[buf][(wm + i * 16 + rr) * 32 + kk];     \
        _Pragma("unroll") for (int i = 0; i < 4; ++i)                          \
            b[i] = *(const short8*)&Bs[buf][(wn + i * 16 + rr) * 32 + kk];     \
        _Pragma("unroll") for (int i = 0; i < 4; ++i)                          \
            _Pragma("unroll") for (int j = 0; j < 4; ++j)                      \
                acc[i][j] = __builtin_amdgcn_mfma_f32_16x16x32_bf16(           \
                    a[i], b[j], acc[i][j], 0, 0, 0);                           \
    } while (0)

    STAGE(0, 0);
    __syncthreads();            // compiler emits vmcnt(0) drain before barrier
    int cur = 0;
    for (int kt = 0; kt < DIN / 32 - 1; ++kt) {
        STAGE(cur ^ 1, kt + 1);  // issue next-tile loads first (overlap MFMA)
        COMPUTE(cur);
        __syncthreads();         // drains vmcnt; next buffer ready
        cur ^= 1;
    }
    COMPUTE(cur);                // last tile, no prefetch

#undef STAGE
#undef COMPUTE

    // epilogue: D[row=(lane>>4)*4+r][col=lane&15]; fused bias; bf16 store
#pragma unroll
    for (int j = 0; j < 4; ++j) {
        const int gc = n0 + wn + j * 16 + rr;
        const float bv = bias[e * DOUT + gc];
#pragma unroll
        for (int i = 0; i < 4; ++i) {
            const int gr = m0 + wm + i * 16 + (lane >> 4) * 4;
            unsigned short* cp = lgts + ((size_t)e * BSZ + gr) * DOUT + gc;
#pragma unroll
            for (int r = 0; r < 4; ++r)
                cp[(size_t)r * DOUT] = f32_to_bf16_rne(acc[i][j][r] + bv);
        }
    }
}

// ---------- 3. row stats: one wave per row; emit rinv4+ev4; atomic Z -------
__global__ __launch_bounds__(256) void rowstats_kernel(
    const unsigned short* __restrict__ lg,
    float4* __restrict__ rinv4, float4* __restrict__ ev4,
    float* __restrict__ Z) {
    __shared__ float4 sz[4];
    const int wv = threadIdx.x >> 6;
    const int b = blockIdx.x * 4 + wv;
    const int lane = threadIdx.x & 63;

    float pe[8];
    float Tv[3], Pv[2], rinv[4];
#pragma unroll
    for (int e = 0; e < NEXP; ++e) {
        short8 v = *(const short8*)&lg[((size_t)e * BSZ + b) * DOUT + lane * 8];
        float l[8];
#pragma unroll
        for (int j = 0; j < 8; ++j) l[j] = bf16_to_f32((unsigned short)v[j]);
        float ss = 0.f;
#pragma unroll
        for (int j = 0; j < 8; ++j) ss += l[j] * l[j];
        ss = wred(ss);
        float ri = 1.0f / fmaxf(sqrtf(ss), 1e-12f);
        rinv[e] = ri;
        float t = 0.f, p = 0.f;
        float ce[8];
#pragma unroll
        for (int j = 0; j < 8; ++j) {
            ce[j] = expf(l[j] * ri);
            t += ce[j];
            if (e > 0) p += pe[j] * ce[j];
        }
        if (e < 3) Tv[e] = wred(t);
        if (e >= 1 && e <= 2) Pv[e - 1] = wred(p);
#pragma unroll
        for (int j = 0; j < 8; ++j) pe[j] = ce[j];
    }

    if (lane == 0) {
        const float d = (float)DOUT;
        float S0 = Tv[0] + d, S1 = Tv[1] + d, S2 = Tv[2] + d;
        float u0 = d / S0, u1 = d / S1, u2 = d / S2;
        float sb0 = Tv[0] / S0, sb1 = Tv[1] / S1, sb2 = Tv[2] / S2;
        float C1 = sb0 * sb1 - Pv[0] / (S0 * S1);
        float C2 = sb1 * sb2 - Pv[1] / (S1 * S2);
        float w1 = u0;
        float w2 = w1 * u1 / (1.0f - C1);
        float w3 = w2 * u2 / (1.0f - C2);
        float4 ev = make_float4(expf(5.0f), expf(5.0f * w1), expf(5.0f * w2),
                                expf(5.0f * w3));
        ev4[b] = ev;
        rinv4[b] = make_float4(rinv[0], rinv[1], rinv[2], rinv[3]);
        sz[wv] = ev;
    }
    __syncthreads();
    if (threadIdx.x == 0) {
        float4 t = sz[0];
        t.x += sz[1].x + sz[2].x + sz[3].x;
        t.y += sz[1].y + sz[2].y + sz[3].y;
        t.z += sz[1].z + sz[2].z + sz[3].z;
        t.w += sz[1].w + sz[2].w + sz[3].w;
        atomicAdd(&Z[0], t.x);
        atomicAdd(&Z[1], t.y);
        atomicAdd(&Z[2], t.z);
        atomicAdd(&Z[3], t.w);
    }
}

// ---------- 4. weighted output: one wave per batch row ----------
__global__ __launch_bounds__(256) void outk_kernel(
    const unsigned short* __restrict__ lg,
    const float4* __restrict__ rinv4, const float4* __restrict__ ev4,
    const float* __restrict__ Z, float* __restrict__ out) {
    const int b = blockIdx.x * 4 + (threadIdx.x >> 6);
    const int lane = threadIdx.x & 63;
    float4 ri = rinv4[b];
    float4 ev = ev4[b];
    float wgt[4] = {ev.x / Z[0] * ri.x, ev.y / Z[1] * ri.y,
                    ev.z / Z[2] * ri.z, ev.w / Z[3] * ri.w};
    float o[8] = {0.f, 0.f, 0.f, 0.f, 0.f, 0.f, 0.f, 0.f};
#pragma unroll
    for (int e = 0; e < NEXP; ++e) {
        short8 v = *(const short8*)&lg[((size_t)e * BSZ + b) * DOUT + lane * 8];
#pragma unroll
        for (int j = 0; j < 8; ++j)
            o[j] += bf16_to_f32((unsigned short)v[j]) * wgt[e];
    }
    float* op = out + (size_t)b * DOUT + lane * 8;
    *(float4*)op = make_float4(o[0], o[1], o[2], o[3]);
    *(float4*)(op + 4) = make_float4(o[4], o[5], o[6], o[7]);
}

// ---------- launch ----------
extern "C" void kernel_launch(void* const* d_in, const int* in_sizes, int n_in,
                              void* d_out, int out_size, void* d_ws,
                              size_t ws_size, hipStream_t stream) {
    const float* x = (const float*)d_in[0];
    const float* W = (const float*)d_in[1];
    const float* bias = (const float*)d_in[2];
    float* out = (float*)d_out;

    char* ws = (char*)d_ws;
    // layout: lgts bf16 [4][8192][512] = 32MB | xb 16MB | wtb 4MB |
    //         rinv4 128KB | ev4 128KB | Z 16B
    unsigned short* lgts = (unsigned short*)ws;
    unsigned short* xb  = (unsigned short*)(ws + (size_t)33554432);
    unsigned short* wtb = (unsigned short*)(ws + (size_t)50331648);
    float4* rinv4 = (float4*)(ws + (size_t)54525952);
    float4* ev4   = (float4*)(ws + (size_t)54525952 + 131072);
    float*  Z     = (float*)(ws + (size_t)54525952 + 262144);

    prep_kernel<<<6144, 256, 0, stream>>>(x, W, xb, wtb, Z);
    gemm_kernel<<<1024, 256, 0, stream>>>(xb, wtb, bias, lgts);
    rowstats_kernel<<<BSZ / 4, 256, 0, stream>>>(lgts, rinv4, ev4, Z);
    outk_kernel<<<BSZ / 4, 256, 0, stream>>>(lgts, rinv4, ev4, Z, out);
}

// Round 9
// 255.069 us; speedup vs baseline: 1.0062x; 1.0062x over previous
//
#include <hip/hip_runtime.h>
#include <hip/hip_bf16.h>

// Shapes (fixed problem)
#define BSZ   8192
#define DIN   1024
#define DOUT  512
#define NEXP  4

typedef __attribute__((ext_vector_type(8))) short short8;
typedef __attribute__((ext_vector_type(4))) float f32x4;

// ---------- helpers ----------
static __device__ inline unsigned short f32_to_bf16_rne(float f) {
    unsigned int u = __float_as_uint(f);
    unsigned int r = 0x7FFFu + ((u >> 16) & 1u);
    u += r;
    return (unsigned short)(u >> 16);
}

static __device__ inline float bf16_to_f32(unsigned short u) {
    return __uint_as_float(((unsigned int)u) << 16);
}

#define GLD_LDS16(g, l)                                                        \
    __builtin_amdgcn_global_load_lds(                                          \
        (const __attribute__((address_space(1))) void*)(g),                    \
        (__attribute__((address_space(3))) void*)(l), 16, 0, 0)

// ---------- 1. prep: x->bf16 | W->Wt bf16 transposed | zero Z --------------
__global__ __launch_bounds__(256) void prep_kernel(
    const float* __restrict__ x, const float* __restrict__ W,
    unsigned short* __restrict__ xb, unsigned short* __restrict__ Wt,
    float* __restrict__ Z) {
    __shared__ float tile[32][33];
    const int bid = blockIdx.x;
    if (bid < 4096) {
        if (bid == 0 && threadIdx.x < 4) Z[threadIdx.x] = 0.0f;
        size_t i = ((size_t)bid * 256 + threadIdx.x) * 8;
        float4 v0 = *(const float4*)&x[i];
        float4 v1 = *(const float4*)&x[i + 4];
        unsigned short tmp[8] = {
            f32_to_bf16_rne(v0.x), f32_to_bf16_rne(v0.y),
            f32_to_bf16_rne(v0.z), f32_to_bf16_rne(v0.w),
            f32_to_bf16_rne(v1.x), f32_to_bf16_rne(v1.y),
            f32_to_bf16_rne(v1.z), f32_to_bf16_rne(v1.w)};
        *(short8*)&xb[i] = *(short8*)tmp;
    } else {
        const int id = bid - 4096;
        const int e = id >> 9;
        const int rem = id & 511;
        const int k0 = (rem >> 4) << 5;
        const int n0 = (rem & 15) << 5;
        const int c = threadIdx.x & 31, r4 = threadIdx.x >> 5;
        const float* Wp = W + ((size_t)e * DIN + k0) * DOUT + n0;
#pragma unroll
        for (int i = 0; i < 4; ++i) {
            int r = r4 + i * 8;
            tile[r][c] = Wp[(size_t)r * DOUT + c];
        }
        __syncthreads();
        unsigned short* Wtp = Wt + ((size_t)e * DOUT + n0) * DIN + k0;
#pragma unroll
        for (int i = 0; i < 4; ++i) {
            int r = r4 + i * 8;
            Wtp[(size_t)r * DIN + c] = f32_to_bf16_rne(tile[c][r]);
        }
    }
}

// ---------- 2. GEMM: 128x128 tile, BK=32, double-buffered LDS (2-phase) ----
__global__ __launch_bounds__(256) void gemm_kernel(
    const unsigned short* __restrict__ xb,
    const unsigned short* __restrict__ wtb,
    const float* __restrict__ bias,
    unsigned short* __restrict__ lgts) {
    __shared__ unsigned short As[2][128 * 32];
    __shared__ unsigned short Bs[2][128 * 32];
    const int tid = threadIdx.x;

    // bijective XCD swizzle (1024 % 8 == 0): each XCD owns 8 m-panels x all (e,n)
    const int bid = blockIdx.x;
    const int swz = (bid & 7) * 128 + (bid >> 3);
    const int mt = swz >> 4;
    const int e  = (swz >> 2) & 3;
    const int nt = swz & 3;
    const int m0 = mt * 128;
    const int n0 = nt * 128;

    const unsigned short* Ag = xb + (size_t)m0 * DIN;
    const unsigned short* Bg = wtb + ((size_t)e * DOUT + n0) * DIN;

    const int lane = tid & 63, w = tid >> 6;
    const int wm = (w >> 1) * 64, wn = (w & 1) * 64;
    const int kk = (lane >> 4) * 8, rr = lane & 15;

    f32x4 acc[4][4] = {};

    const int f = tid;
    const int row0 = f >> 2, seg0 = f & 3;
    const int f1 = 256 + tid;
    const int row1 = f1 >> 2, seg1 = f1 & 3;

#define STAGE(buf, kt)                                                         \
    do {                                                                       \
        const int k0_ = (kt) * 32;                                             \
        GLD_LDS16(Ag + (size_t)row0 * DIN + k0_ + seg0 * 8, &As[buf][f * 8]);  \
        GLD_LDS16(Bg + (size_t)row0 * DIN + k0_ + seg0 * 8, &Bs[buf][f * 8]);  \
        GLD_LDS16(Ag + (size_t)row1 * DIN + k0_ + seg1 * 8, &As[buf][f1 * 8]); \
        GLD_LDS16(Bg + (size_t)row1 * DIN + k0_ + seg1 * 8, &Bs[buf][f1 * 8]); \
    } while (0)

#define COMPUTE(buf)                                                           \
    do {                                                                       \
        short8 a[4], b[4];                                                     \
        _Pragma("unroll") for (int i = 0; i < 4; ++i)                          \
            a[i] = *(const short8*)&As[buf][(wm + i * 16 + rr) * 32 + kk];     \
        _Pragma("unroll") for (int i = 0; i < 4; ++i)                          \
            b[i] = *(const short8*)&Bs[buf][(wn + i * 16 + rr) * 32 + kk];     \
        _Pragma("unroll") for (int i = 0; i < 4; ++i)                          \
            _Pragma("unroll") for (int j = 0; j < 4; ++j)                      \
                acc[i][j] = __builtin_amdgcn_mfma_f32_16x16x32_bf16(           \
                    a[i], b[j], acc[i][j], 0, 0, 0);                           \
    } while (0)

    STAGE(0, 0);
    __syncthreads();
    int cur = 0;
    for (int kt = 0; kt < DIN / 32 - 1; ++kt) {
        STAGE(cur ^ 1, kt + 1);  // issue next-tile loads first (overlap MFMA)
        COMPUTE(cur);
        __syncthreads();
        cur ^= 1;
    }
    COMPUTE(cur);

#undef STAGE
#undef COMPUTE

    // epilogue: D[row=(lane>>4)*4+r][col=lane&15]; fused bias; bf16 store
#pragma unroll
    for (int j = 0; j < 4; ++j) {
        const int gc = n0 + wn + j * 16 + rr;
        const float bv = bias[e * DOUT + gc];
#pragma unroll
        for (int i = 0; i < 4; ++i) {
            const int gr = m0 + wm + i * 16 + (lane >> 4) * 4;
            unsigned short* cp = lgts + ((size_t)e * BSZ + gr) * DOUT + gc;
#pragma unroll
            for (int r = 0; r < 4; ++r)
                cp[(size_t)r * DOUT] = f32_to_bf16_rne(acc[i][j][r] + bv);
        }
    }
}

// ---------- 3. row stats: one wave/row, BATCHED reductions ----------
// Two interleaved shuffle-reduction phases instead of 9 serial chains:
// phase 1: ss[0..3] (4 independent chains); phase 2: T0,T1,T2,P01,P12 (5).
__global__ __launch_bounds__(256) void rowstats_kernel(
    const unsigned short* __restrict__ lg,
    float4* __restrict__ rinv4, float4* __restrict__ ev4,
    float* __restrict__ Z) {
    __shared__ float4 sz[4];
    const int wv = threadIdx.x >> 6;
    const int b = blockIdx.x * 4 + wv;
    const int lane = threadIdx.x & 63;

    // load all 4 experts' fragments of this row (keep packed: 16 VGPRs)
    short8 v[4];
#pragma unroll
    for (int e = 0; e < NEXP; ++e)
        v[e] = *(const short8*)&lg[((size_t)e * BSZ + b) * DOUT + lane * 8];

    // per-lane partial sum-of-squares, all experts
    float ss[4];
#pragma unroll
    for (int e = 0; e < NEXP; ++e) {
        float s = 0.f;
#pragma unroll
        for (int j = 0; j < 8; ++j) {
            float xv = bf16_to_f32((unsigned short)v[e][j]);
            s += xv * xv;
        }
        ss[e] = s;
    }
    // phase 1: 4 independent chains interleaved -> latency of ~one chain
#pragma unroll
    for (int off = 1; off < 64; off <<= 1) {
#pragma unroll
        for (int e = 0; e < NEXP; ++e) ss[e] += __shfl_xor(ss[e], off, 64);
    }
    float ri[4];
#pragma unroll
    for (int e = 0; e < NEXP; ++e) ri[e] = 1.0f / fmaxf(sqrtf(ss[e]), 1e-12f);

    // exp(xi) for experts 0..2 only (expert 3's alpha never used downstream)
    float ce[3][8];
#pragma unroll
    for (int e = 0; e < 3; ++e)
#pragma unroll
        for (int j = 0; j < 8; ++j)
            ce[e][j] = expf(bf16_to_f32((unsigned short)v[e][j]) * ri[e]);

    // partials: T0,T1,T2,P01,P12
    float red[5] = {0.f, 0.f, 0.f, 0.f, 0.f};
#pragma unroll
    for (int j = 0; j < 8; ++j) {
        red[0] += ce[0][j];
        red[1] += ce[1][j];
        red[2] += ce[2][j];
        red[3] += ce[0][j] * ce[1][j];
        red[4] += ce[1][j] * ce[2][j];
    }
    // phase 2: 5 independent chains interleaved
#pragma unroll
    for (int off = 1; off < 64; off <<= 1) {
#pragma unroll
        for (int r = 0; r < 5; ++r) red[r] += __shfl_xor(red[r], off, 64);
    }

    if (lane == 0) {
        const float d = (float)DOUT;
        float S0 = red[0] + d, S1 = red[1] + d, S2 = red[2] + d;
        float u0 = d / S0, u1 = d / S1, u2 = d / S2;
        float sb0 = red[0] / S0, sb1 = red[1] / S1, sb2 = red[2] / S2;
        float C1 = sb0 * sb1 - red[3] / (S0 * S1);
        float C2 = sb1 * sb2 - red[4] / (S1 * S2);
        float w1 = u0;
        float w2 = w1 * u1 / (1.0f - C1);
        float w3 = w2 * u2 / (1.0f - C2);
        float4 ev = make_float4(expf(5.0f), expf(5.0f * w1), expf(5.0f * w2),
                                expf(5.0f * w3));
        ev4[b] = ev;
        rinv4[b] = make_float4(ri[0], ri[1], ri[2], ri[3]);
        sz[wv] = ev;
    }
    __syncthreads();
    if (threadIdx.x == 0) {
        float4 t = sz[0];
        t.x += sz[1].x + sz[2].x + sz[3].x;
        t.y += sz[1].y + sz[2].y + sz[3].y;
        t.z += sz[1].z + sz[2].z + sz[3].z;
        t.w += sz[1].w + sz[2].w + sz[3].w;
        atomicAdd(&Z[0], t.x);
        atomicAdd(&Z[1], t.y);
        atomicAdd(&Z[2], t.z);
        atomicAdd(&Z[3], t.w);
    }
}

// ---------- 4. weighted output: one wave per batch row ----------
__global__ __launch_bounds__(256) void outk_kernel(
    const unsigned short* __restrict__ lg,
    const float4* __restrict__ rinv4, const float4* __restrict__ ev4,
    const float* __restrict__ Z, float* __restrict__ out) {
    const int b = blockIdx.x * 4 + (threadIdx.x >> 6);
    const int lane = threadIdx.x & 63;
    float4 ri = rinv4[b];
    float4 ev = ev4[b];
    float wgt[4] = {ev.x / Z[0] * ri.x, ev.y / Z[1] * ri.y,
                    ev.z / Z[2] * ri.z, ev.w / Z[3] * ri.w};
    float o[8] = {0.f, 0.f, 0.f, 0.f, 0.f, 0.f, 0.f, 0.f};
#pragma unroll
    for (int e = 0; e < NEXP; ++e) {
        short8 v = *(const short8*)&lg[((size_t)e * BSZ + b) * DOUT + lane * 8];
#pragma unroll
        for (int j = 0; j < 8; ++j)
            o[j] += bf16_to_f32((unsigned short)v[j]) * wgt[e];
    }
    float* op = out + (size_t)b * DOUT + lane * 8;
    *(float4*)op = make_float4(o[0], o[1], o[2], o[3]);
    *(float4*)(op + 4) = make_float4(o[4], o[5], o[6], o[7]);
}

// ---------- launch ----------
extern "C" void kernel_launch(void* const* d_in, const int* in_sizes, int n_in,
                              void* d_out, int out_size, void* d_ws,
                              size_t ws_size, hipStream_t stream) {
    const float* x = (const float*)d_in[0];
    const float* W = (const float*)d_in[1];
    const float* bias = (const float*)d_in[2];
    float* out = (float*)d_out;

    char* ws = (char*)d_ws;
    // layout: lgts bf16 [4][8192][512] = 32MB | xb 16MB | wtb 4MB |
    //         rinv4 128KB | ev4 128KB | Z 16B
    unsigned short* lgts = (unsigned short*)ws;
    unsigned short* xb  = (unsigned short*)(ws + (size_t)33554432);
    unsigned short* wtb = (unsigned short*)(ws + (size_t)50331648);
    float4* rinv4 = (float4*)(ws + (size_t)54525952);
    float4* ev4   = (float4*)(ws + (size_t)54525952 + 131072);
    float*  Z     = (float*)(ws + (size_t)54525952 + 262144);

    prep_kernel<<<6144, 256, 0, stream>>>(x, W, xb, wtb, Z);
    gemm_kernel<<<1024, 256, 0, stream>>>(xb, wtb, bias, lgts);
    rowstats_kernel<<<BSZ / 4, 256, 0, stream>>>(lgts, rinv4, ev4, Z);
    outk_kernel<<<BSZ / 4, 256, 0, stream>>>(lgts, rinv4, ev4, Z, out);
}

// Round 10
// 159.620 us; speedup vs baseline: 1.6079x; 1.5980x over previous
//
#include <hip/hip_runtime.h>
#include <hip/hip_bf16.h>

// Shapes (fixed problem)
#define BSZ   8192
#define DIN   1024
#define DOUT  512
#define NEXP  4
#define ZSLOTS 256

typedef __attribute__((ext_vector_type(8))) short short8;
typedef __attribute__((ext_vector_type(4))) float f32x4;

// ---------- helpers ----------
static __device__ inline unsigned short f32_to_bf16_rne(float f) {
    unsigned int u = __float_as_uint(f);
    unsigned int r = 0x7FFFu + ((u >> 16) & 1u);
    u += r;
    return (unsigned short)(u >> 16);
}

static __device__ inline float bf16_to_f32(unsigned short u) {
    return __uint_as_float(((unsigned int)u) << 16);
}

#define GLD_LDS16(g, l)                                                        \
    __builtin_amdgcn_global_load_lds(                                          \
        (const __attribute__((address_space(1))) void*)(g),                    \
        (__attribute__((address_space(3))) void*)(l), 16, 0, 0)

// ---------- 1. prep: x->bf16 | W->Wt bf16 transposed | zero Zsh ------------
__global__ __launch_bounds__(256) void prep_kernel(
    const float* __restrict__ x, const float* __restrict__ W,
    unsigned short* __restrict__ xb, unsigned short* __restrict__ Wt,
    float4* __restrict__ Zsh) {
    __shared__ float tile[32][33];
    const int bid = blockIdx.x;
    if (bid < 4096) {
        if (bid == 0) Zsh[threadIdx.x] = make_float4(0.f, 0.f, 0.f, 0.f);
        size_t i = ((size_t)bid * 256 + threadIdx.x) * 8;
        float4 v0 = *(const float4*)&x[i];
        float4 v1 = *(const float4*)&x[i + 4];
        unsigned short tmp[8] = {
            f32_to_bf16_rne(v0.x), f32_to_bf16_rne(v0.y),
            f32_to_bf16_rne(v0.z), f32_to_bf16_rne(v0.w),
            f32_to_bf16_rne(v1.x), f32_to_bf16_rne(v1.y),
            f32_to_bf16_rne(v1.z), f32_to_bf16_rne(v1.w)};
        *(short8*)&xb[i] = *(short8*)tmp;
    } else {
        const int id = bid - 4096;
        const int e = id >> 9;
        const int rem = id & 511;
        const int k0 = (rem >> 4) << 5;
        const int n0 = (rem & 15) << 5;
        const int c = threadIdx.x & 31, r4 = threadIdx.x >> 5;
        const float* Wp = W + ((size_t)e * DIN + k0) * DOUT + n0;
#pragma unroll
        for (int i = 0; i < 4; ++i) {
            int r = r4 + i * 8;
            tile[r][c] = Wp[(size_t)r * DOUT + c];
        }
        __syncthreads();
        unsigned short* Wtp = Wt + ((size_t)e * DOUT + n0) * DIN + k0;
#pragma unroll
        for (int i = 0; i < 4; ++i) {
            int r = r4 + i * 8;
            Wtp[(size_t)r * DIN + c] = f32_to_bf16_rne(tile[c][r]);
        }
    }
}

// ---------- 2. GEMM: 128x128 tile, BK=32, double-buffered LDS (2-phase) ----
__global__ __launch_bounds__(256) void gemm_kernel(
    const unsigned short* __restrict__ xb,
    const unsigned short* __restrict__ wtb,
    const float* __restrict__ bias,
    unsigned short* __restrict__ lgts) {
    __shared__ unsigned short As[2][128 * 32];
    __shared__ unsigned short Bs[2][128 * 32];
    const int tid = threadIdx.x;

    // bijective XCD swizzle (1024 % 8 == 0): each XCD owns 8 m-panels x all (e,n)
    const int bid = blockIdx.x;
    const int swz = (bid & 7) * 128 + (bid >> 3);
    const int mt = swz >> 4;
    const int e  = (swz >> 2) & 3;
    const int nt = swz & 3;
    const int m0 = mt * 128;
    const int n0 = nt * 128;

    const unsigned short* Ag = xb + (size_t)m0 * DIN;
    const unsigned short* Bg = wtb + ((size_t)e * DOUT + n0) * DIN;

    const int lane = tid & 63, w = tid >> 6;
    const int wm = (w >> 1) * 64, wn = (w & 1) * 64;
    const int kk = (lane >> 4) * 8, rr = lane & 15;

    f32x4 acc[4][4] = {};

    const int f = tid;
    const int row0 = f >> 2, seg0 = f & 3;
    const int f1 = 256 + tid;
    const int row1 = f1 >> 2, seg1 = f1 & 3;

#define STAGE(buf, kt)                                                         \
    do {                                                                       \
        const int k0_ = (kt) * 32;                                             \
        GLD_LDS16(Ag + (size_t)row0 * DIN + k0_ + seg0 * 8, &As[buf][f * 8]);  \
        GLD_LDS16(Bg + (size_t)row0 * DIN + k0_ + seg0 * 8, &Bs[buf][f * 8]);  \
        GLD_LDS16(Ag + (size_t)row1 * DIN + k0_ + seg1 * 8, &As[buf][f1 * 8]); \
        GLD_LDS16(Bg + (size_t)row1 * DIN + k0_ + seg1 * 8, &Bs[buf][f1 * 8]); \
    } while (0)

#define COMPUTE(buf)                                                           \
    do {                                                                       \
        short8 a[4], b[4];                                                     \
        _Pragma("unroll") for (int i = 0; i < 4; ++i)                          \
            a[i] = *(const short8*)&As[buf][(wm + i * 16 + rr) * 32 + kk];     \
        _Pragma("unroll") for (int i = 0; i < 4; ++i)                          \
            b[i] = *(const short8*)&Bs[buf][(wn + i * 16 + rr) * 32 + kk];     \
        _Pragma("unroll") for (int i = 0; i < 4; ++i)                          \
            _Pragma("unroll") for (int j = 0; j < 4; ++j)                      \
                acc[i][j] = __builtin_amdgcn_mfma_f32_16x16x32_bf16(           \
                    a[i], b[j], acc[i][j], 0, 0, 0);                           \
    } while (0)

    STAGE(0, 0);
    __syncthreads();
    int cur = 0;
    for (int kt = 0; kt < DIN / 32 - 1; ++kt) {
        STAGE(cur ^ 1, kt + 1);  // issue next-tile loads first (overlap MFMA)
        COMPUTE(cur);
        __syncthreads();
        cur ^= 1;
    }
    COMPUTE(cur);

#undef STAGE
#undef COMPUTE

    // epilogue: D[row=(lane>>4)*4+r][col=lane&15]; fused bias; bf16 store
#pragma unroll
    for (int j = 0; j < 4; ++j) {
        const int gc = n0 + wn + j * 16 + rr;
        const float bv = bias[e * DOUT + gc];
#pragma unroll
        for (int i = 0; i < 4; ++i) {
            const int gr = m0 + wm + i * 16 + (lane >> 4) * 4;
            unsigned short* cp = lgts + ((size_t)e * BSZ + gr) * DOUT + gc;
#pragma unroll
            for (int r = 0; r < 4; ++r)
                cp[(size_t)r * DOUT] = f32_to_bf16_rne(acc[i][j][r] + bv);
        }
    }
}

// ---------- 3. row stats: one wave/row, batched reductions, SPREAD atomics -
__global__ __launch_bounds__(256) void rowstats_kernel(
    const unsigned short* __restrict__ lg,
    float4* __restrict__ rinv4, float4* __restrict__ ev4,
    float4* __restrict__ Zsh) {
    __shared__ float4 sz[4];
    const int wv = threadIdx.x >> 6;
    const int b = blockIdx.x * 4 + wv;
    const int lane = threadIdx.x & 63;

    short8 v[4];
#pragma unroll
    for (int e = 0; e < NEXP; ++e)
        v[e] = *(const short8*)&lg[((size_t)e * BSZ + b) * DOUT + lane * 8];

    float ss[4];
#pragma unroll
    for (int e = 0; e < NEXP; ++e) {
        float s = 0.f;
#pragma unroll
        for (int j = 0; j < 8; ++j) {
            float xv = bf16_to_f32((unsigned short)v[e][j]);
            s += xv * xv;
        }
        ss[e] = s;
    }
#pragma unroll
    for (int off = 1; off < 64; off <<= 1) {
#pragma unroll
        for (int e = 0; e < NEXP; ++e) ss[e] += __shfl_xor(ss[e], off, 64);
    }
    float ri[4];
#pragma unroll
    for (int e = 0; e < NEXP; ++e) ri[e] = 1.0f / fmaxf(sqrtf(ss[e]), 1e-12f);

    float ce[3][8];
#pragma unroll
    for (int e = 0; e < 3; ++e)
#pragma unroll
        for (int j = 0; j < 8; ++j)
            ce[e][j] = expf(bf16_to_f32((unsigned short)v[e][j]) * ri[e]);

    float red[5] = {0.f, 0.f, 0.f, 0.f, 0.f};
#pragma unroll
    for (int j = 0; j < 8; ++j) {
        red[0] += ce[0][j];
        red[1] += ce[1][j];
        red[2] += ce[2][j];
        red[3] += ce[0][j] * ce[1][j];
        red[4] += ce[1][j] * ce[2][j];
    }
#pragma unroll
    for (int off = 1; off < 64; off <<= 1) {
#pragma unroll
        for (int r = 0; r < 5; ++r) red[r] += __shfl_xor(red[r], off, 64);
    }

    if (lane == 0) {
        const float d = (float)DOUT;
        float S0 = red[0] + d, S1 = red[1] + d, S2 = red[2] + d;
        float u0 = d / S0, u1 = d / S1, u2 = d / S2;
        float sb0 = red[0] / S0, sb1 = red[1] / S1, sb2 = red[2] / S2;
        float C1 = sb0 * sb1 - red[3] / (S0 * S1);
        float C2 = sb1 * sb2 - red[4] / (S1 * S2);
        float w1 = u0;
        float w2 = w1 * u1 / (1.0f - C1);
        float w3 = w2 * u2 / (1.0f - C2);
        float4 ev = make_float4(expf(5.0f), expf(5.0f * w1), expf(5.0f * w2),
                                expf(5.0f * w3));
        ev4[b] = ev;
        rinv4[b] = make_float4(ri[0], ri[1], ri[2], ri[3]);
        sz[wv] = ev;
    }
    __syncthreads();
    // one slot per block (bid&255): 8192 atomics spread over 64 cache lines
    if (threadIdx.x == 0) {
        float4 t = sz[0];
        t.x += sz[1].x + sz[2].x + sz[3].x;
        t.y += sz[1].y + sz[2].y + sz[3].y;
        t.z += sz[1].z + sz[2].z + sz[3].z;
        t.w += sz[1].w + sz[2].w + sz[3].w;
        float* zp = (float*)&Zsh[blockIdx.x & (ZSLOTS - 1)];
        atomicAdd(zp + 0, t.x);
        atomicAdd(zp + 1, t.y);
        atomicAdd(zp + 2, t.z);
        atomicAdd(zp + 3, t.w);
    }
}

// ---------- 4. weighted output: reduce Zsh in wave 0, then weighted sum ----
__global__ __launch_bounds__(256) void outk_kernel(
    const unsigned short* __restrict__ lg,
    const float4* __restrict__ rinv4, const float4* __restrict__ ev4,
    const float4* __restrict__ Zsh, float* __restrict__ out) {
    __shared__ float4 zls;
    const int tid = threadIdx.x;
    if (tid < 64) {
        float4 s = make_float4(0.f, 0.f, 0.f, 0.f);
#pragma unroll
        for (int i = 0; i < ZSLOTS / 64; ++i) {
            float4 p = Zsh[tid + i * 64];
            s.x += p.x; s.y += p.y; s.z += p.z; s.w += p.w;
        }
#pragma unroll
        for (int off = 1; off < 64; off <<= 1) {
            s.x += __shfl_xor(s.x, off, 64);
            s.y += __shfl_xor(s.y, off, 64);
            s.z += __shfl_xor(s.z, off, 64);
            s.w += __shfl_xor(s.w, off, 64);
        }
        if (tid == 0) zls = s;
    }
    __syncthreads();
    const float4 Zt = zls;

    const int b = blockIdx.x * 4 + (tid >> 6);
    const int lane = tid & 63;
    float4 ri = rinv4[b];
    float4 ev = ev4[b];
    float wgt[4] = {ev.x / Zt.x * ri.x, ev.y / Zt.y * ri.y,
                    ev.z / Zt.z * ri.z, ev.w / Zt.w * ri.w};
    float o[8] = {0.f, 0.f, 0.f, 0.f, 0.f, 0.f, 0.f, 0.f};
#pragma unroll
    for (int e = 0; e < NEXP; ++e) {
        short8 v = *(const short8*)&lg[((size_t)e * BSZ + b) * DOUT + lane * 8];
#pragma unroll
        for (int j = 0; j < 8; ++j)
            o[j] += bf16_to_f32((unsigned short)v[j]) * wgt[e];
    }
    float* op = out + (size_t)b * DOUT + lane * 8;
    *(float4*)op = make_float4(o[0], o[1], o[2], o[3]);
    *(float4*)(op + 4) = make_float4(o[4], o[5], o[6], o[7]);
}

// ---------- launch ----------
extern "C" void kernel_launch(void* const* d_in, const int* in_sizes, int n_in,
                              void* d_out, int out_size, void* d_ws,
                              size_t ws_size, hipStream_t stream) {
    const float* x = (const float*)d_in[0];
    const float* W = (const float*)d_in[1];
    const float* bias = (const float*)d_in[2];
    float* out = (float*)d_out;

    char* ws = (char*)d_ws;
    // layout: lgts bf16 [4][8192][512] = 32MB | xb 16MB | wtb 4MB |
    //         rinv4 128KB | ev4 128KB | Zsh 4KB
    unsigned short* lgts = (unsigned short*)ws;
    unsigned short* xb  = (unsigned short*)(ws + (size_t)33554432);
    unsigned short* wtb = (unsigned short*)(ws + (size_t)50331648);
    float4* rinv4 = (float4*)(ws + (size_t)54525952);
    float4* ev4   = (float4*)(ws + (size_t)54525952 + 131072);
    float4* Zsh   = (float4*)(ws + (size_t)54525952 + 262144);

    prep_kernel<<<6144, 256, 0, stream>>>(x, W, xb, wtb, Zsh);
    gemm_kernel<<<1024, 256, 0, stream>>>(xb, wtb, bias, lgts);
    rowstats_kernel<<<BSZ / 4, 256, 0, stream>>>(lgts, rinv4, ev4, Zsh);
    outk_kernel<<<BSZ / 4, 256, 0, stream>>>(lgts, rinv4, ev4, Zsh, out);
}

// Round 12
// 156.451 us; speedup vs baseline: 1.6405x; 1.0203x over previous
//
#include <hip/hip_runtime.h>
#include <hip/hip_bf16.h>

// Shapes (fixed problem)
#define BSZ   8192
#define DIN   1024
#define DOUT  512
#define NEXP  4
#define ZSLOTS 256
#define NKT   (DIN / 32)   // 32 K-steps

typedef __attribute__((ext_vector_type(8))) short short8;
typedef __attribute__((ext_vector_type(4))) float f32x4;

// ---------- helpers ----------
static __device__ inline unsigned short f32_to_bf16_rne(float f) {
    unsigned int u = __float_as_uint(f);
    unsigned int r = 0x7FFFu + ((u >> 16) & 1u);
    u += r;
    return (unsigned short)(u >> 16);
}

static __device__ inline float bf16_to_f32(unsigned short u) {
    return __uint_as_float(((unsigned int)u) << 16);
}

#define GLD_LDS16(g, l)                                                        \
    __builtin_amdgcn_global_load_lds(                                          \
        (const __attribute__((address_space(1))) void*)(g),                    \
        (__attribute__((address_space(3))) void*)(l), 16, 0, 0)

// ---------- 1. prep: x->bf16 | W->Wt bf16 transposed | zero Zsh ------------
__global__ __launch_bounds__(256) void prep_kernel(
    const float* __restrict__ x, const float* __restrict__ W,
    unsigned short* __restrict__ xb, unsigned short* __restrict__ Wt,
    float4* __restrict__ Zsh) {
    __shared__ float tile[32][33];
    const int bid = blockIdx.x;
    if (bid < 4096) {
        if (bid == 0) Zsh[threadIdx.x] = make_float4(0.f, 0.f, 0.f, 0.f);
        size_t i = ((size_t)bid * 256 + threadIdx.x) * 8;
        float4 v0 = *(const float4*)&x[i];
        float4 v1 = *(const float4*)&x[i + 4];
        unsigned short tmp[8] = {
            f32_to_bf16_rne(v0.x), f32_to_bf16_rne(v0.y),
            f32_to_bf16_rne(v0.z), f32_to_bf16_rne(v0.w),
            f32_to_bf16_rne(v1.x), f32_to_bf16_rne(v1.y),
            f32_to_bf16_rne(v1.z), f32_to_bf16_rne(v1.w)};
        *(short8*)&xb[i] = *(short8*)tmp;
    } else {
        const int id = bid - 4096;
        const int e = id >> 9;
        const int rem = id & 511;
        const int k0 = (rem >> 4) << 5;
        const int n0 = (rem & 15) << 5;
        const int c = threadIdx.x & 31, r4 = threadIdx.x >> 5;
        const float* Wp = W + ((size_t)e * DIN + k0) * DOUT + n0;
#pragma unroll
        for (int i = 0; i < 4; ++i) {
            int r = r4 + i * 8;
            tile[r][c] = Wp[(size_t)r * DOUT + c];
        }
        __syncthreads();
        unsigned short* Wtp = Wt + ((size_t)e * DOUT + n0) * DIN + k0;
#pragma unroll
        for (int i = 0; i < 4; ++i) {
            int r = r4 + i * 8;
            Wtp[(size_t)r * DIN + c] = f32_to_bf16_rne(tile[c][r]);
        }
    }
}

// ---------- 2. GEMM: 128x128 tile, BK=32, 3-buffer LDS, counted vmcnt ------
// Prefetch distance 2: loads drained at each barrier are >= 1 full K-step old
// (HBM latency fully hidden); the 4 just-issued loads stay in flight across
// the barrier (raw s_barrier + asm vmcnt(4), never vmcnt(0) in steady state).
__global__ __launch_bounds__(256) void gemm_kernel(
    const unsigned short* __restrict__ xb,
    const unsigned short* __restrict__ wtb,
    const float* __restrict__ bias,
    unsigned short* __restrict__ lgts) {
    __shared__ unsigned short As[3][128 * 32];
    __shared__ unsigned short Bs[3][128 * 32];
    const int tid = threadIdx.x;

    // bijective XCD swizzle (1024 % 8 == 0): each XCD owns 8 m-panels x all (e,n)
    const int bid = blockIdx.x;
    const int swz = (bid & 7) * 128 + (bid >> 3);
    const int mt = swz >> 4;
    const int e  = (swz >> 2) & 3;
    const int nt = swz & 3;
    const int m0 = mt * 128;
    const int n0 = nt * 128;

    const unsigned short* Ag = xb + (size_t)m0 * DIN;
    const unsigned short* Bg = wtb + ((size_t)e * DOUT + n0) * DIN;

    const int lane = tid & 63, w = tid >> 6;
    const int wm = (w >> 1) * 64, wn = (w & 1) * 64;
    const int kk = (lane >> 4) * 8, rr = lane & 15;

    f32x4 acc[4][4] = {};

    const int f = tid;
    const int row0 = f >> 2, seg0 = f & 3;
    const int f1 = 256 + tid;
    const int row1 = f1 >> 2, seg1 = f1 & 3;

#define STAGE(buf, kt)                                                         \
    do {                                                                       \
        const int k0_ = (kt) * 32;                                             \
        GLD_LDS16(Ag + (size_t)row0 * DIN + k0_ + seg0 * 8, &As[buf][f * 8]);  \
        GLD_LDS16(Bg + (size_t)row0 * DIN + k0_ + seg0 * 8, &Bs[buf][f * 8]);  \
        GLD_LDS16(Ag + (size_t)row1 * DIN + k0_ + seg1 * 8, &As[buf][f1 * 8]); \
        GLD_LDS16(Bg + (size_t)row1 * DIN + k0_ + seg1 * 8, &Bs[buf][f1 * 8]); \
    } while (0)

#define COMPUTE(buf)                                                           \
    do {                                                                       \
        short8 a[4], b[4];                                                     \
        _Pragma("unroll") for (int i = 0; i < 4; ++i)                          \
            a[i] = *(const short8*)&As[buf][(wm + i * 16 + rr) * 32 + kk];     \
        _Pragma("unroll") for (int i = 0; i < 4; ++i)                          \
            b[i] = *(const short8*)&Bs[buf][(wn + i * 16 + rr) * 32 + kk];     \
        _Pragma("unroll") for (int i = 0; i < 4; ++i)                          \
            _Pragma("unroll") for (int j = 0; j < 4; ++j)                      \
                acc[i][j] = __builtin_amdgcn_mfma_f32_16x16x32_bf16(           \
                    a[i], b[j], acc[i][j], 0, 0, 0);                           \
    } while (0)

#define WAITBAR(N)                                                             \
    do {                                                                       \
        asm volatile("s_waitcnt vmcnt(" #N ")" ::: "memory");                  \
        __builtin_amdgcn_s_barrier();                                          \
        __builtin_amdgcn_sched_barrier(0);                                     \
    } while (0)

    // prologue: stage tiles 0,1; drain tile0's 4 loads (oldest), keep tile1's
    STAGE(0, 0);
    STAGE(1, 1);
    WAITBAR(4);

    int cb = 0, sb = 2;
    for (int kt = 0; kt < NKT - 2; ++kt) {
        STAGE(sb, kt + 2);   // into buffer last read at kt-1 (fenced by barrier)
        COMPUTE(cb);         // its loads drained at previous barrier
        WAITBAR(4);          // drain tile kt+1's loads; keep kt+2's in flight
        cb = (cb == 2) ? 0 : cb + 1;
        sb = (sb == 2) ? 0 : sb + 1;
    }
    COMPUTE(cb);             // tile NKT-2
    WAITBAR(0);              // drain last tile's loads
    cb = (cb == 2) ? 0 : cb + 1;
    COMPUTE(cb);             // tile NKT-1

#undef STAGE
#undef COMPUTE
#undef WAITBAR

    // epilogue: D[row=(lane>>4)*4+r][col=lane&15]; fused bias; bf16 store
#pragma unroll
    for (int j = 0; j < 4; ++j) {
        const int gc = n0 + wn + j * 16 + rr;
        const float bv = bias[e * DOUT + gc];
#pragma unroll
        for (int i = 0; i < 4; ++i) {
            const int gr = m0 + wm + i * 16 + (lane >> 4) * 4;
            unsigned short* cp = lgts + ((size_t)e * BSZ + gr) * DOUT + gc;
#pragma unroll
            for (int r = 0; r < 4; ++r)
                cp[(size_t)r * DOUT] = f32_to_bf16_rne(acc[i][j][r] + bv);
        }
    }
}

// ---------- 3. row stats: one wave/row, batched reductions, SPREAD atomics -
__global__ __launch_bounds__(256) void rowstats_kernel(
    const unsigned short* __restrict__ lg,
    float4* __restrict__ rinv4, float4* __restrict__ ev4,
    float4* __restrict__ Zsh) {
    __shared__ float4 sz[4];
    const int wv = threadIdx.x >> 6;
    const int b = blockIdx.x * 4 + wv;
    const int lane = threadIdx.x & 63;

    short8 v[4];
#pragma unroll
    for (int e = 0; e < NEXP; ++e)
        v[e] = *(const short8*)&lg[((size_t)e * BSZ + b) * DOUT + lane * 8];

    float ss[4];
#pragma unroll
    for (int e = 0; e < NEXP; ++e) {
        float s = 0.f;
#pragma unroll
        for (int j = 0; j < 8; ++j) {
            float xv = bf16_to_f32((unsigned short)v[e][j]);
            s += xv * xv;
        }
        ss[e] = s;
    }
#pragma unroll
    for (int off = 1; off < 64; off <<= 1) {
#pragma unroll
        for (int e = 0; e < NEXP; ++e) ss[e] += __shfl_xor(ss[e], off, 64);
    }
    float ri[4];
#pragma unroll
    for (int e = 0; e < NEXP; ++e) ri[e] = 1.0f / fmaxf(sqrtf(ss[e]), 1e-12f);

    float ce[3][8];
#pragma unroll
    for (int e = 0; e < 3; ++e)
#pragma unroll
        for (int j = 0; j < 8; ++j)
            ce[e][j] = expf(bf16_to_f32((unsigned short)v[e][j]) * ri[e]);

    float red[5] = {0.f, 0.f, 0.f, 0.f, 0.f};
#pragma unroll
    for (int j = 0; j < 8; ++j) {
        red[0] += ce[0][j];
        red[1] += ce[1][j];
        red[2] += ce[2][j];
        red[3] += ce[0][j] * ce[1][j];
        red[4] += ce[1][j] * ce[2][j];
    }
#pragma unroll
    for (int off = 1; off < 64; off <<= 1) {
#pragma unroll
        for (int r = 0; r < 5; ++r) red[r] += __shfl_xor(red[r], off, 64);
    }

    if (lane == 0) {
        const float d = (float)DOUT;
        float S0 = red[0] + d, S1 = red[1] + d, S2 = red[2] + d;
        float u0 = d / S0, u1 = d / S1, u2 = d / S2;
        float sb0 = red[0] / S0, sb1 = red[1] / S1, sb2 = red[2] / S2;
        float C1 = sb0 * sb1 - red[3] / (S0 * S1);
        float C2 = sb1 * sb2 - red[4] / (S1 * S2);
        float w1 = u0;
        float w2 = w1 * u1 / (1.0f - C1);
        float w3 = w2 * u2 / (1.0f - C2);
        float4 ev = make_float4(expf(5.0f), expf(5.0f * w1), expf(5.0f * w2),
                                expf(5.0f * w3));
        ev4[b] = ev;
        rinv4[b] = make_float4(ri[0], ri[1], ri[2], ri[3]);
        sz[wv] = ev;
    }
    __syncthreads();
    // one slot per block (bid&255): 8192 atomics spread over 64 cache lines
    if (threadIdx.x == 0) {
        float4 t = sz[0];
        t.x += sz[1].x + sz[2].x + sz[3].x;
        t.y += sz[1].y + sz[2].y + sz[3].y;
        t.z += sz[1].z + sz[2].z + sz[3].z;
        t.w += sz[1].w + sz[2].w + sz[3].w;
        float* zp = (float*)&Zsh[blockIdx.x & (ZSLOTS - 1)];
        atomicAdd(zp + 0, t.x);
        atomicAdd(zp + 1, t.y);
        atomicAdd(zp + 2, t.z);
        atomicAdd(zp + 3, t.w);
    }
}

// ---------- 4. weighted output: reduce Zsh in wave 0, then weighted sum ----
__global__ __launch_bounds__(256) void outk_kernel(
    const unsigned short* __restrict__ lg,
    const float4* __restrict__ rinv4, const float4* __restrict__ ev4,
    const float4* __restrict__ Zsh, float* __restrict__ out) {
    __shared__ float4 zls;
    const int tid = threadIdx.x;
    if (tid < 64) {
        float4 s = make_float4(0.f, 0.f, 0.f, 0.f);
#pragma unroll
        for (int i = 0; i < ZSLOTS / 64; ++i) {
            float4 p = Zsh[tid + i * 64];
            s.x += p.x; s.y += p.y; s.z += p.z; s.w += p.w;
        }
#pragma unroll
        for (int off = 1; off < 64; off <<= 1) {
            s.x += __shfl_xor(s.x, off, 64);
            s.y += __shfl_xor(s.y, off, 64);
            s.z += __shfl_xor(s.z, off, 64);
            s.w += __shfl_xor(s.w, off, 64);
        }
        if (tid == 0) zls = s;
    }
    __syncthreads();
    const float4 Zt = zls;

    const int b = blockIdx.x * 4 + (tid >> 6);
    const int lane = tid & 63;
    float4 ri = rinv4[b];
    float4 ev = ev4[b];
    float wgt[4] = {ev.x / Zt.x * ri.x, ev.y / Zt.y * ri.y,
                    ev.z / Zt.z * ri.z, ev.w / Zt.w * ri.w};
    float o[8] = {0.f, 0.f, 0.f, 0.f, 0.f, 0.f, 0.f, 0.f};
#pragma unroll
    for (int e = 0; e < NEXP; ++e) {
        short8 v = *(const short8*)&lg[((size_t)e * BSZ + b) * DOUT + lane * 8];
#pragma unroll
        for (int j = 0; j < 8; ++j)
            o[j] += bf16_to_f32((unsigned short)v[j]) * wgt[e];
    }
    float* op = out + (size_t)b * DOUT + lane * 8;
    *(float4*)op = make_float4(o[0], o[1], o[2], o[3]);
    *(float4*)(op + 4) = make_float4(o[4], o[5], o[6], o[7]);
}

// ---------- launch ----------
extern "C" void kernel_launch(void* const* d_in, const int* in_sizes, int n_in,
                              void* d_out, int out_size, void* d_ws,
                              size_t ws_size, hipStream_t stream) {
    const float* x = (const float*)d_in[0];
    const float* W = (const float*)d_in[1];
    const float* bias = (const float*)d_in[2];
    float* out = (float*)d_out;

    char* ws = (char*)d_ws;
    // layout: lgts bf16 [4][8192][512] = 32MB | xb 16MB | wtb 4MB |
    //         rinv4 128KB | ev4 128KB | Zsh 4KB
    unsigned short* lgts = (unsigned short*)ws;
    unsigned short* xb  = (unsigned short*)(ws + (size_t)33554432);
    unsigned short* wtb = (unsigned short*)(ws + (size_t)50331648);
    float4* rinv4 = (float4*)(ws + (size_t)54525952);
    float4* ev4   = (float4*)(ws + (size_t)54525952 + 131072);
    float4* Zsh   = (float4*)(ws + (size_t)54525952 + 262144);

    prep_kernel<<<6144, 256, 0, stream>>>(x, W, xb, wtb, Zsh);
    gemm_kernel<<<1024, 256, 0, stream>>>(xb, wtb, bias, lgts);
    rowstats_kernel<<<BSZ / 4, 256, 0, stream>>>(lgts, rinv4, ev4, Zsh);
    outk_kernel<<<BSZ / 4, 256, 0, stream>>>(lgts, rinv4, ev4, Zsh, out);
}